// Round 1
// baseline (2037.315 us; speedup 1.0000x reference)
//
#include <hip/hip_runtime.h>
#include <hip/hip_bf16.h>
#include <float.h>

#define B_ 2
#define N_ 2048
#define DIM_ 1024
#define HEADS_ 8
#define DH_ 64
#define NUM_MEM_ 4
#define ROWS_ (B_ * N_)          // 4096
#define QCOLS_ (HEADS_ * DH_)    // 512
#define JTOT_ (N_ + NUM_MEM_)    // 2052

// ---------------- LayerNorm: one block per row (1024 elems) ----------------
__global__ __launch_bounds__(256) void ln_kernel(const float* __restrict__ x,
                                                 const float* __restrict__ gamma,
                                                 float* __restrict__ xn) {
    int row = blockIdx.x;
    const float4 v = ((const float4*)(x + (size_t)row * DIM_))[threadIdx.x];
    float s  = v.x + v.y + v.z + v.w;
    float s2 = v.x * v.x + v.y * v.y + v.z * v.z + v.w * v.w;
    #pragma unroll
    for (int off = 32; off > 0; off >>= 1) {
        s  += __shfl_down(s, off);
        s2 += __shfl_down(s2, off);
    }
    __shared__ float ws1[4], ws2[4];
    int lane = threadIdx.x & 63, wid = threadIdx.x >> 6;
    if (lane == 0) { ws1[wid] = s; ws2[wid] = s2; }
    __syncthreads();
    float tot  = ws1[0] + ws1[1] + ws1[2] + ws1[3];
    float tot2 = ws2[0] + ws2[1] + ws2[2] + ws2[3];
    float mu  = tot * (1.0f / DIM_);
    float var = tot2 * (1.0f / DIM_) - mu * mu;
    float rs  = rsqrtf(var + 1e-5f);
    const float4 g = ((const float4*)gamma)[threadIdx.x];
    float4 o;
    o.x = (v.x - mu) * rs * g.x;
    o.y = (v.y - mu) * rs * g.y;
    o.z = (v.z - mu) * rs * g.z;
    o.w = (v.w - mu) * rs * g.w;
    ((float4*)(xn + (size_t)row * DIM_))[threadIdx.x] = o;
}

// ---------------- f32 SGEMM: C[M,N] = scale * (A[M,K] @ B[K,N]) ----------------
// 64x64 tile, BK=16, 256 threads, 4x4 per-thread microtile. M%64==N%64==K%16==0.
__global__ __launch_bounds__(256) void sgemm64(const float* __restrict__ A,
                                               const float* __restrict__ Bm,
                                               float* __restrict__ C,
                                               int M, int N, int K, float scale) {
    __shared__ float As[16][64];
    __shared__ float Bs[16][64];
    int tid = threadIdx.x;
    int tx = tid & 15, ty = tid >> 4;
    int r0 = blockIdx.y * 64, c0 = blockIdx.x * 64;
    // A tile load mapping: 64 rows x 16 cols; lane-major rows for conflict-free LDS store
    int arow = tid & 63, acol = (tid >> 6) * 4;
    // B tile load mapping: 16 rows x 64 cols
    int brow = tid >> 4, bcol = (tid & 15) * 4;
    float acc[4][4] = {};
    for (int k0 = 0; k0 < K; k0 += 16) {
        float4 a = *(const float4*)(A + (size_t)(r0 + arow) * K + k0 + acol);
        float4 b = *(const float4*)(Bm + (size_t)(k0 + brow) * N + c0 + bcol);
        As[acol + 0][arow] = a.x;
        As[acol + 1][arow] = a.y;
        As[acol + 2][arow] = a.z;
        As[acol + 3][arow] = a.w;
        *(float4*)&Bs[brow][bcol] = b;
        __syncthreads();
        #pragma unroll
        for (int kk = 0; kk < 16; ++kk) {
            float av[4], bv[4];
            *(float4*)av = *(const float4*)&As[kk][ty * 4];
            *(float4*)bv = *(const float4*)&Bs[kk][tx * 4];
            #pragma unroll
            for (int i2 = 0; i2 < 4; ++i2)
                #pragma unroll
                for (int j2 = 0; j2 < 4; ++j2)
                    acc[i2][j2] = fmaf(av[i2], bv[j2], acc[i2][j2]);
        }
        __syncthreads();
    }
    #pragma unroll
    for (int i2 = 0; i2 < 4; ++i2) {
        float4 o = { acc[i2][0] * scale, acc[i2][1] * scale,
                     acc[i2][2] * scale, acc[i2][3] * scale };
        *(float4*)(C + (size_t)(r0 + ty * 4 + i2) * N + c0 + tx * 4) = o;
    }
}

// ---------------- Attention: one block per (b, h, query row) ----------------
__global__ __launch_bounds__(256) void attn_kernel(const float* __restrict__ q,
                                                   const float* __restrict__ kv,
                                                   const float* __restrict__ mem_kv,
                                                   const float* __restrict__ bias,
                                                   const int* __restrict__ mask,
                                                   float* __restrict__ attn_out) {
    __shared__ float s[JTOT_];
    __shared__ float qrow[DH_];
    __shared__ float red[4][DH_];
    __shared__ float rmax[4], rsum[4];
    int idx = blockIdx.x;
    int i = idx % N_;
    int h = (idx / N_) % HEADS_;
    int b = idx / (N_ * HEADS_);
    int tid = threadIdx.x;
    int cnt = i + NUM_MEM_ + 1;  // allowed keys: j' in [0, i+NUM_MEM]

    if (tid < DH_) qrow[tid] = q[((size_t)(b * N_ + i)) * QCOLS_ + h * DH_ + tid];
    __syncthreads();

    float lmax = -FLT_MAX;
    for (int j = tid; j < cnt; j += 256) {
        const float* kp;
        float bb;
        bool m;
        if (j < NUM_MEM_) {
            kp = mem_kv + j * DH_;   // mem_kv[0]
            bb = 0.f;
            m = true;
        } else {
            int sj = j - NUM_MEM_;
            kp = kv + ((size_t)(b * N_ + sj)) * (2 * DH_);
            bb = bias[((size_t)h * N_ + i) * N_ + sj];
            m = mask[b * N_ + sj] != 0;
        }
        float d = 0.f;
        #pragma unroll
        for (int t = 0; t < DH_; ++t) d = fmaf(qrow[t], kp[t], d);
        float val = m ? (d + bb) : -FLT_MAX;
        s[j] = val;
        lmax = fmaxf(lmax, val);
    }
    #pragma unroll
    for (int off = 32; off > 0; off >>= 1) lmax = fmaxf(lmax, __shfl_down(lmax, off));
    int lane = tid & 63, wid = tid >> 6;
    if (lane == 0) rmax[wid] = lmax;
    __syncthreads();
    float mx = fmaxf(fmaxf(rmax[0], rmax[1]), fmaxf(rmax[2], rmax[3]));

    float lsum = 0.f;
    for (int j = tid; j < cnt; j += 256) {
        float e = expf(s[j] - mx);
        s[j] = e;
        lsum += e;
    }
    #pragma unroll
    for (int off = 32; off > 0; off >>= 1) lsum += __shfl_down(lsum, off);
    if (lane == 0) rsum[wid] = lsum;
    __syncthreads();
    float inv = 1.f / (rsum[0] + rsum[1] + rsum[2] + rsum[3]);

    int d = tid & 63, ch = tid >> 6;
    float acc = 0.f;
    for (int j = ch; j < cnt; j += 4) {
        const float* vp = (j < NUM_MEM_)
            ? (mem_kv + NUM_MEM_ * DH_ + j * DH_)                       // mem_kv[1]
            : (kv + ((size_t)(b * N_ + (j - NUM_MEM_))) * (2 * DH_) + DH_);
        acc = fmaf(s[j], vp[d], acc);
    }
    red[ch][d] = acc;
    __syncthreads();
    if (tid < DH_) {
        float o = (red[0][tid] + red[1][tid] + red[2][tid] + red[3][tid]) * inv;
        attn_out[((size_t)(b * N_ + i)) * QCOLS_ + h * DH_ + tid] = o;
    }
}

extern "C" void kernel_launch(void* const* d_in, const int* in_sizes, int n_in,
                              void* d_out, int out_size, void* d_ws, size_t ws_size,
                              hipStream_t stream) {
    const float* x         = (const float*)d_in[0];
    const float* attn_bias = (const float*)d_in[1];
    const float* gamma     = (const float*)d_in[2];
    const float* Wq        = (const float*)d_in[3];
    const float* Wkv       = (const float*)d_in[4];
    const float* mem_kv    = (const float*)d_in[5];
    const float* Wout      = (const float*)d_in[6];
    const int*   mask      = (const int*)d_in[7];
    float* out = (float*)d_out;

    float* w = (float*)d_ws;
    float* xn      = w;                       // 4096*1024
    float* q       = xn + (size_t)ROWS_ * DIM_;        // 4096*512
    float* kv      = q + (size_t)ROWS_ * QCOLS_;       // 4096*128
    float* attn_o  = kv + (size_t)ROWS_ * 2 * DH_;     // 4096*512

    ln_kernel<<<ROWS_, 256, 0, stream>>>(x, gamma, xn);
    sgemm64<<<dim3(QCOLS_ / 64, ROWS_ / 64), 256, 0, stream>>>(xn, Wq, q, ROWS_, QCOLS_, DIM_, 0.125f);
    sgemm64<<<dim3((2 * DH_) / 64, ROWS_ / 64), 256, 0, stream>>>(x, Wkv, kv, ROWS_, 2 * DH_, DIM_, 1.0f);
    attn_kernel<<<B_ * HEADS_ * N_, 256, 0, stream>>>(q, kv, mem_kv, attn_bias, mask, attn_o);
    sgemm64<<<dim3(DIM_ / 64, ROWS_ / 64), 256, 0, stream>>>(attn_o, Wout, out, ROWS_, DIM_, QCOLS_, 1.0f);
}

// Round 2
// 385.621 us; speedup vs baseline: 5.2832x; 5.2832x over previous
//
#include <hip/hip_runtime.h>
#include <hip/hip_bf16.h>
#include <float.h>

#define B_ 2
#define N_ 2048
#define DIM_ 1024
#define HEADS_ 8
#define DH_ 64
#define NUM_MEM_ 4
#define ROWS_ (B_ * N_)          // 4096
#define QCOLS_ (HEADS_ * DH_)    // 512
#define JTOT_ (N_ + NUM_MEM_)    // 2052
#define JPAD_ 2112               // 33 * 64
#define KPAD_ 72                 // LDS row length (bf16 elems), +8 pad

typedef __attribute__((ext_vector_type(8))) short short8v;
typedef __attribute__((ext_vector_type(4))) float f32x4;

// ---------------- LayerNorm ----------------
__global__ __launch_bounds__(256) void ln_kernel(const float* __restrict__ x,
                                                 const float* __restrict__ gamma,
                                                 float* __restrict__ xn) {
    int row = blockIdx.x;
    const float4 v = ((const float4*)(x + (size_t)row * DIM_))[threadIdx.x];
    float s  = v.x + v.y + v.z + v.w;
    float s2 = v.x * v.x + v.y * v.y + v.z * v.z + v.w * v.w;
    #pragma unroll
    for (int off = 32; off > 0; off >>= 1) {
        s  += __shfl_down(s, off);
        s2 += __shfl_down(s2, off);
    }
    __shared__ float ws1[4], ws2[4];
    int lane = threadIdx.x & 63, wid = threadIdx.x >> 6;
    if (lane == 0) { ws1[wid] = s; ws2[wid] = s2; }
    __syncthreads();
    float tot  = ws1[0] + ws1[1] + ws1[2] + ws1[3];
    float tot2 = ws2[0] + ws2[1] + ws2[2] + ws2[3];
    float mu  = tot * (1.0f / DIM_);
    float var = tot2 * (1.0f / DIM_) - mu * mu;
    float rs  = rsqrtf(var + 1e-5f);
    const float4 g = ((const float4*)gamma)[threadIdx.x];
    float4 o;
    o.x = (v.x - mu) * rs * g.x;
    o.y = (v.y - mu) * rs * g.y;
    o.z = (v.z - mu) * rs * g.z;
    o.w = (v.w - mu) * rs * g.w;
    ((float4*)(xn + (size_t)row * DIM_))[threadIdx.x] = o;
}

// ---------------- f32 SGEMM (64x64 tile) ----------------
__global__ __launch_bounds__(256) void sgemm64(const float* __restrict__ A,
                                               const float* __restrict__ Bm,
                                               float* __restrict__ C,
                                               int M, int N, int K, float scale) {
    __shared__ float As[16][64];
    __shared__ float Bs[16][64];
    int tid = threadIdx.x;
    int tx = tid & 15, ty = tid >> 4;
    int r0 = blockIdx.y * 64, c0 = blockIdx.x * 64;
    int arow = tid & 63, acol = (tid >> 6) * 4;
    int brow = tid >> 4, bcol = (tid & 15) * 4;
    float acc[4][4] = {};
    for (int k0 = 0; k0 < K; k0 += 16) {
        float4 a = *(const float4*)(A + (size_t)(r0 + arow) * K + k0 + acol);
        float4 b = *(const float4*)(Bm + (size_t)(k0 + brow) * N + c0 + bcol);
        As[acol + 0][arow] = a.x;
        As[acol + 1][arow] = a.y;
        As[acol + 2][arow] = a.z;
        As[acol + 3][arow] = a.w;
        *(float4*)&Bs[brow][bcol] = b;
        __syncthreads();
        #pragma unroll
        for (int kk = 0; kk < 16; ++kk) {
            float av[4], bv[4];
            *(float4*)av = *(const float4*)&As[kk][ty * 4];
            *(float4*)bv = *(const float4*)&Bs[kk][tx * 4];
            #pragma unroll
            for (int i2 = 0; i2 < 4; ++i2)
                #pragma unroll
                for (int j2 = 0; j2 < 4; ++j2)
                    acc[i2][j2] = fmaf(av[i2], bv[j2], acc[i2][j2]);
        }
        __syncthreads();
    }
    #pragma unroll
    for (int i2 = 0; i2 < 4; ++i2) {
        float4 o = { acc[i2][0] * scale, acc[i2][1] * scale,
                     acc[i2][2] * scale, acc[i2][3] * scale };
        *(float4*)(C + (size_t)(r0 + ty * 4 + i2) * N + c0 + tx * 4) = o;
    }
}

// ---------------- cast q (f32) -> qb (bf16 bits in ushort) ----------------
__global__ __launch_bounds__(256) void cast_q_kernel(const float* __restrict__ q,
                                                     ushort* __restrict__ qb) {
    int t = blockIdx.x * 256 + threadIdx.x;
    const float4* src = (const float4*)(q + (size_t)t * 8);
    float4 a = src[0], b = src[1];
    ushort u[8];
    float f[8] = {a.x, a.y, a.z, a.w, b.x, b.y, b.z, b.w};
    #pragma unroll
    for (int k = 0; k < 8; ++k) {
        __hip_bfloat16 hb = __float2bfloat16(f[k]);
        u[k] = *(ushort*)&hb;
    }
    *(int4*)(qb + (size_t)t * 8) = *(int4*)u;
}

// ---------------- build padded K (bf16) and V^T (bf16) with mem slots ----------------
__global__ __launch_bounds__(256) void build_kv_kernel(const float* __restrict__ kv,
                                                       const float* __restrict__ mem_kv,
                                                       ushort* __restrict__ Kb,
                                                       ushort* __restrict__ Vt) {
    int t = blockIdx.x * 256 + threadIdx.x;    // over B_*JPAD_*DH_
    int d = t & 63;
    int j = (t >> 6) % JPAD_;
    int b = t / (JPAD_ * DH_);
    float kval = 0.f, vval = 0.f;
    if (j < NUM_MEM_) {
        kval = mem_kv[j * DH_ + d];
        vval = mem_kv[NUM_MEM_ * DH_ + j * DH_ + d];
    } else if (j < JTOT_) {
        int sj = j - NUM_MEM_;
        kval = kv[((size_t)(b * N_ + sj)) * (2 * DH_) + d];
        vval = kv[((size_t)(b * N_ + sj)) * (2 * DH_) + DH_ + d];
    }
    __hip_bfloat16 hk = __float2bfloat16(kval);
    __hip_bfloat16 hv = __float2bfloat16(vval);
    Kb[((size_t)(b * JPAD_) + j) * DH_ + d] = *(ushort*)&hk;
    Vt[((size_t)(b * DH_) + d) * JPAD_ + j] = *(ushort*)&hv;
}

// ---------------- flash attention, bf16 MFMA ----------------
__global__ __launch_bounds__(256) void fattn_kernel(const ushort* __restrict__ qb,
                                                    const ushort* __restrict__ Kb,
                                                    const ushort* __restrict__ Vt,
                                                    const float* __restrict__ bias,
                                                    const int* __restrict__ mask,
                                                    float* __restrict__ attn_out) {
    __shared__ ushort Ks[64][KPAD_];
    __shared__ ushort Vs[64][KPAD_];      // Vs[d][j_local]
    __shared__ ushort Ps[4][16][KPAD_];   // per-wave P tile

    // balanced (b,h,qt) decode: batch-1 blocks get mirrored q-tiles
    int bid = blockIdx.x;
    int b   = bid >> 8;
    int rem = bid & 255;
    int h   = rem >> 5;
    int qtr = rem & 31;
    int qt  = b ? (31 - qtr) : qtr;
    int q0  = qt * 64;

    int tid = threadIdx.x;
    int w  = tid >> 6;
    int l  = tid & 63;
    int lg = l >> 4;      // lane group 0..3
    int ll = l & 15;

    // Q fragments (A operand): row = ll, k = lg*8 + r (+32*c)
    short8v aq0, aq1;
    {
        int i = q0 + w * 16 + ll;
        const ushort* qp = qb + ((size_t)(b * N_ + i)) * QCOLS_ + h * DH_;
        aq0 = *(const short8v*)(qp + lg * 8);
        aq1 = *(const short8v*)(qp + 32 + lg * 8);
    }

    f32x4 oacc[4] = {};          // 4 d-tiles; row = lg*4+r, col(d) = dt*16+ll
    float mrow[4], lsum[4];
    #pragma unroll
    for (int r = 0; r < 4; ++r) { mrow[r] = -1e30f; lsum[r] = 0.f; }

    int ntiles = (q0 + 67) / 64 + 1;
    for (int jt = 0; jt < ntiles; ++jt) {
        int j0 = jt * 64;
        __syncthreads();
        {   // stage K tile and V^T tile: 8 bf16 per thread per row-half
            int r = tid >> 3, c = (tid & 7) * 8;
            *(int4*)&Ks[r][c]      = *(const int4*)(Kb + ((size_t)(b * JPAD_) + j0 + r) * DH_ + c);
            *(int4*)&Ks[r + 32][c] = *(const int4*)(Kb + ((size_t)(b * JPAD_) + j0 + r + 32) * DH_ + c);
            *(int4*)&Vs[r][c]      = *(const int4*)(Vt + ((size_t)(b * DH_) + r) * JPAD_ + j0 + c);
            *(int4*)&Vs[r + 32][c] = *(const int4*)(Vt + ((size_t)(b * DH_) + r + 32) * JPAD_ + j0 + c);
        }
        __syncthreads();

        // S = Q @ K^T + bias, masked
        float sv[4][4];
        #pragma unroll
        for (int ct = 0; ct < 4; ++ct) {
            f32x4 acc = {};
            short8v bk0 = *(const short8v*)&Ks[ct * 16 + ll][lg * 8];
            short8v bk1 = *(const short8v*)&Ks[ct * 16 + ll][32 + lg * 8];
            acc = __builtin_amdgcn_mfma_f32_16x16x32_bf16(aq0, bk0, acc, 0, 0, 0);
            acc = __builtin_amdgcn_mfma_f32_16x16x32_bf16(aq1, bk1, acc, 0, 0, 0);
            int jj = j0 + ct * 16 + ll;
            #pragma unroll
            for (int r = 0; r < 4; ++r) {
                int i = q0 + w * 16 + lg * 4 + r;
                float s;
                if (jj <= i + NUM_MEM_) {
                    if (jj >= NUM_MEM_) {
                        int sj = jj - NUM_MEM_;
                        float bb = bias[((size_t)h * N_ + i) * N_ + sj];
                        s = mask[b * N_ + sj] ? acc[r] + bb : -1e30f;
                    } else {
                        s = acc[r];
                    }
                } else {
                    s = -1e30f;
                }
                sv[ct][r] = s;
            }
        }

        // online softmax
        float scale_[4];
        #pragma unroll
        for (int r = 0; r < 4; ++r) {
            float t = fmaxf(fmaxf(sv[0][r], sv[1][r]), fmaxf(sv[2][r], sv[3][r]));
            #pragma unroll
            for (int off = 1; off < 16; off <<= 1) t = fmaxf(t, __shfl_xor(t, off));
            float mn = fmaxf(mrow[r], t);
            scale_[r] = __expf(mrow[r] - mn);
            mrow[r] = mn;
        }
        float psum[4] = {0.f, 0.f, 0.f, 0.f};
        #pragma unroll
        for (int ct = 0; ct < 4; ++ct) {
            #pragma unroll
            for (int r = 0; r < 4; ++r) {
                float p = __expf(sv[ct][r] - mrow[r]);
                psum[r] += p;
                __hip_bfloat16 hb = __float2bfloat16(p);
                Ps[w][lg * 4 + r][ct * 16 + ll] = *(ushort*)&hb;
            }
        }
        #pragma unroll
        for (int r = 0; r < 4; ++r) {
            float t = psum[r];
            #pragma unroll
            for (int off = 1; off < 16; off <<= 1) t += __shfl_xor(t, off);
            lsum[r] = lsum[r] * scale_[r] + t;
        }
        #pragma unroll
        for (int dt = 0; dt < 4; ++dt)
            #pragma unroll
            for (int r = 0; r < 4; ++r) oacc[dt][r] *= scale_[r];

        // O += P @ V   (A = P chunks, B = V via V^T LDS reads)
        #pragma unroll
        for (int c = 0; c < 2; ++c) {
            short8v ap = *(const short8v*)&Ps[w][ll][c * 32 + lg * 8];
            #pragma unroll
            for (int dt = 0; dt < 4; ++dt) {
                short8v bv = *(const short8v*)&Vs[dt * 16 + ll][c * 32 + lg * 8];
                oacc[dt] = __builtin_amdgcn_mfma_f32_16x16x32_bf16(ap, bv, oacc[dt], 0, 0, 0);
            }
        }
    }

    #pragma unroll
    for (int dt = 0; dt < 4; ++dt) {
        #pragma unroll
        for (int r = 0; r < 4; ++r) {
            int i = q0 + w * 16 + lg * 4 + r;
            attn_out[((size_t)(b * N_ + i)) * QCOLS_ + h * DH_ + dt * 16 + ll] =
                oacc[dt][r] / lsum[r];
        }
    }
}

extern "C" void kernel_launch(void* const* d_in, const int* in_sizes, int n_in,
                              void* d_out, int out_size, void* d_ws, size_t ws_size,
                              hipStream_t stream) {
    const float* x         = (const float*)d_in[0];
    const float* attn_bias = (const float*)d_in[1];
    const float* gamma     = (const float*)d_in[2];
    const float* Wq        = (const float*)d_in[3];
    const float* Wkv       = (const float*)d_in[4];
    const float* mem_kv    = (const float*)d_in[5];
    const float* Wout      = (const float*)d_in[6];
    const int*   mask      = (const int*)d_in[7];
    float* out = (float*)d_out;

    char* wsb = (char*)d_ws;
    float*  xn     = (float*)wsb;                         // [0, 16MB) — freed after gemmQ
    ushort* qb     = (ushort*)wsb;                        // reuse [0, 4MB)
    ushort* Kb     = (ushort*)(wsb + (4u << 20));         // 540KB
    ushort* Vt     = (ushort*)(wsb + (5u << 20));         // 540KB
    float*  q      = (float*)(wsb + (16u << 20));         // 8MB
    float*  kv     = (float*)(wsb + (24u << 20));         // 2MB
    float*  attn_o = (float*)(wsb + (26u << 20));         // 8MB

    ln_kernel<<<ROWS_, 256, 0, stream>>>(x, gamma, xn);
    sgemm64<<<dim3(QCOLS_ / 64, ROWS_ / 64), 256, 0, stream>>>(xn, Wq, q, ROWS_, QCOLS_, DIM_, 0.125f);
    cast_q_kernel<<<(ROWS_ * QCOLS_) / (256 * 8), 256, 0, stream>>>(q, qb);
    sgemm64<<<dim3((2 * DH_) / 64, ROWS_ / 64), 256, 0, stream>>>(x, Wkv, kv, ROWS_, 2 * DH_, DIM_, 1.0f);
    build_kv_kernel<<<(B_ * JPAD_ * DH_) / 256, 256, 0, stream>>>(kv, mem_kv, Kb, Vt);
    fattn_kernel<<<B_ * HEADS_ * (N_ / 64), 256, 0, stream>>>(qb, Kb, Vt, attn_bias, mask, attn_o);
    sgemm64<<<dim3(DIM_ / 64, ROWS_ / 64), 256, 0, stream>>>(attn_o, Wout, out, ROWS_, DIM_, QCOLS_, 1.0f);
}

// Round 3
// 264.008 us; speedup vs baseline: 7.7169x; 1.4606x over previous
//
#include <hip/hip_runtime.h>
#include <hip/hip_bf16.h>
#include <float.h>

#define B_ 2
#define N_ 2048
#define DIM_ 1024
#define HEADS_ 8
#define DH_ 64
#define NUM_MEM_ 4
#define ROWS_ (B_ * N_)          // 4096
#define QCOLS_ (HEADS_ * DH_)    // 512
#define JTOT_ (N_ + NUM_MEM_)    // 2052
#define JPAD_ 2112               // 33 * 64
#define KPAD_ 72                 // LDS row length (bf16 elems), +8 pad

typedef __attribute__((ext_vector_type(8))) short short8v;
typedef __attribute__((ext_vector_type(4))) float f32x4;

// ---------------- LayerNorm ----------------
__global__ __launch_bounds__(256) void ln_kernel(const float* __restrict__ x,
                                                 const float* __restrict__ gamma,
                                                 float* __restrict__ xn) {
    int row = blockIdx.x;
    const float4 v = ((const float4*)(x + (size_t)row * DIM_))[threadIdx.x];
    float s  = v.x + v.y + v.z + v.w;
    float s2 = v.x * v.x + v.y * v.y + v.z * v.z + v.w * v.w;
    #pragma unroll
    for (int off = 32; off > 0; off >>= 1) {
        s  += __shfl_down(s, off);
        s2 += __shfl_down(s2, off);
    }
    __shared__ float ws1[4], ws2[4];
    int lane = threadIdx.x & 63, wid = threadIdx.x >> 6;
    if (lane == 0) { ws1[wid] = s; ws2[wid] = s2; }
    __syncthreads();
    float tot  = ws1[0] + ws1[1] + ws1[2] + ws1[3];
    float tot2 = ws2[0] + ws2[1] + ws2[2] + ws2[3];
    float mu  = tot * (1.0f / DIM_);
    float var = tot2 * (1.0f / DIM_) - mu * mu;
    float rs  = rsqrtf(var + 1e-5f);
    const float4 g = ((const float4*)gamma)[threadIdx.x];
    float4 o;
    o.x = (v.x - mu) * rs * g.x;
    o.y = (v.y - mu) * rs * g.y;
    o.z = (v.z - mu) * rs * g.z;
    o.w = (v.w - mu) * rs * g.w;
    ((float4*)(xn + (size_t)row * DIM_))[threadIdx.x] = o;
}

// ---------------- f32 SGEMM (64x64 tile) ----------------
__global__ __launch_bounds__(256) void sgemm64(const float* __restrict__ A,
                                               const float* __restrict__ Bm,
                                               float* __restrict__ C,
                                               int M, int N, int K, float scale) {
    __shared__ float As[16][64];
    __shared__ float Bs[16][64];
    int tid = threadIdx.x;
    int tx = tid & 15, ty = tid >> 4;
    int r0 = blockIdx.y * 64, c0 = blockIdx.x * 64;
    int arow = tid & 63, acol = (tid >> 6) * 4;
    int brow = tid >> 4, bcol = (tid & 15) * 4;
    float acc[4][4] = {};
    for (int k0 = 0; k0 < K; k0 += 16) {
        float4 a = *(const float4*)(A + (size_t)(r0 + arow) * K + k0 + acol);
        float4 b = *(const float4*)(Bm + (size_t)(k0 + brow) * N + c0 + bcol);
        As[acol + 0][arow] = a.x;
        As[acol + 1][arow] = a.y;
        As[acol + 2][arow] = a.z;
        As[acol + 3][arow] = a.w;
        *(float4*)&Bs[brow][bcol] = b;
        __syncthreads();
        #pragma unroll
        for (int kk = 0; kk < 16; ++kk) {
            float av[4], bv[4];
            *(float4*)av = *(const float4*)&As[kk][ty * 4];
            *(float4*)bv = *(const float4*)&Bs[kk][tx * 4];
            #pragma unroll
            for (int i2 = 0; i2 < 4; ++i2)
                #pragma unroll
                for (int j2 = 0; j2 < 4; ++j2)
                    acc[i2][j2] = fmaf(av[i2], bv[j2], acc[i2][j2]);
        }
        __syncthreads();
    }
    #pragma unroll
    for (int i2 = 0; i2 < 4; ++i2) {
        float4 o = { acc[i2][0] * scale, acc[i2][1] * scale,
                     acc[i2][2] * scale, acc[i2][3] * scale };
        *(float4*)(C + (size_t)(r0 + ty * 4 + i2) * N + c0 + tx * 4) = o;
    }
}

// ---------------- cast q (f32) -> qb (bf16 bits in ushort) ----------------
__global__ __launch_bounds__(256) void cast_q_kernel(const float* __restrict__ q,
                                                     ushort* __restrict__ qb) {
    int t = blockIdx.x * 256 + threadIdx.x;
    const float4* src = (const float4*)(q + (size_t)t * 8);
    float4 a = src[0], b = src[1];
    ushort u[8];
    float f[8] = {a.x, a.y, a.z, a.w, b.x, b.y, b.z, b.w};
    #pragma unroll
    for (int k = 0; k < 8; ++k) {
        __hip_bfloat16 hb = __float2bfloat16(f[k]);
        u[k] = *(ushort*)&hb;
    }
    *(int4*)(qb + (size_t)t * 8) = *(int4*)u;
}

// ---------------- build padded K (bf16) and V^T (bf16) with mem slots ----------------
__global__ __launch_bounds__(256) void build_kv_kernel(const float* __restrict__ kv,
                                                       const float* __restrict__ mem_kv,
                                                       ushort* __restrict__ Kb,
                                                       ushort* __restrict__ Vt) {
    int t = blockIdx.x * 256 + threadIdx.x;    // over B_*JPAD_*DH_
    int d = t & 63;
    int j = (t >> 6) % JPAD_;
    int b = t / (JPAD_ * DH_);
    float kval = 0.f, vval = 0.f;
    if (j < NUM_MEM_) {
        kval = mem_kv[j * DH_ + d];
        vval = mem_kv[NUM_MEM_ * DH_ + j * DH_ + d];
    } else if (j < JTOT_) {
        int sj = j - NUM_MEM_;
        kval = kv[((size_t)(b * N_ + sj)) * (2 * DH_) + d];
        vval = kv[((size_t)(b * N_ + sj)) * (2 * DH_) + DH_ + d];
    }
    __hip_bfloat16 hk = __float2bfloat16(kval);
    __hip_bfloat16 hv = __float2bfloat16(vval);
    Kb[((size_t)(b * JPAD_) + j) * DH_ + d] = *(ushort*)&hk;
    Vt[((size_t)(b * DH_) + d) * JPAD_ + j] = *(ushort*)&hv;
}

// ---------------- flash attention, bf16 MFMA, pipelined ----------------
__global__ __launch_bounds__(256) void fattn_kernel(const ushort* __restrict__ qb,
                                                    const ushort* __restrict__ Kb,
                                                    const ushort* __restrict__ Vt,
                                                    const float* __restrict__ bias,
                                                    const int* __restrict__ mask,
                                                    float* __restrict__ attn_out) {
    __shared__ ushort Ks[64][KPAD_];
    __shared__ ushort Vs[64][KPAD_];      // Vs[d][j_local]
    __shared__ ushort Ps[4][16][KPAD_];   // per-wave P tile

    // balanced (b,h,qt) decode: batch-1 blocks get mirrored q-tiles;
    // block c and c+256 co-locate on a CU -> per-CU work ~constant (35 tiles)
    int bid = blockIdx.x;
    int b   = bid >> 8;
    int rem = bid & 255;
    int h   = rem >> 5;
    int qtr = rem & 31;
    int qt  = b ? (31 - qtr) : qtr;
    int q0  = qt * 64;

    int tid = threadIdx.x;
    int w  = tid >> 6;
    int l  = tid & 63;
    int lg = l >> 4;      // lane group 0..3
    int ll = l & 15;
    int i_base = q0 + w * 16;

    // Q fragments (A operand): row = ll, k = lg*8 + r (+32*c)
    short8v aq0, aq1;
    {
        int i = i_base + ll;
        const ushort* qp = qb + ((size_t)(b * N_ + i)) * QCOLS_ + h * DH_;
        aq0 = *(const short8v*)(qp + lg * 8);
        aq1 = *(const short8v*)(qp + 32 + lg * 8);
    }

    // per-lane loop-invariant bias row pointers (i fixed per r slot)
    const float* brow0 = bias + ((size_t)h * N_ + i_base + lg * 4 + 0) * N_;
    const float* brow1 = bias + ((size_t)h * N_ + i_base + lg * 4 + 1) * N_;
    const float* brow2 = bias + ((size_t)h * N_ + i_base + lg * 4 + 2) * N_;
    const float* brow3 = bias + ((size_t)h * N_ + i_base + lg * 4 + 3) * N_;
    const int* mrowp = mask + b * N_;

    int ntiles = (q0 + 67) / 64 + 1;

    // staging mapping: 32 rows x 64 cols per int4 (8 threads cover a row)
    int sr = tid >> 3, sc = (tid & 7) * 8;
    const ushort* KbB = Kb + (size_t)b * JPAD_ * DH_;
    const ushort* VtB = Vt + (size_t)b * DH_ * JPAD_;

    // ---- prologue: prefetch tile 0 (K/V into regs, bias/mask into regs) ----
    int4 kr0 = *(const int4*)(KbB + (size_t)sr * DH_ + sc);
    int4 kr1 = *(const int4*)(KbB + (size_t)(sr + 32) * DH_ + sc);
    int4 vr0 = *(const int4*)(VtB + (size_t)sr * JPAD_ + sc);
    int4 vr1 = *(const int4*)(VtB + (size_t)(sr + 32) * JPAD_ + sc);
    float bbc[16];
    int   mkc[4];
    #pragma unroll
    for (int ct = 0; ct < 4; ++ct) {
        int jj = ct * 16 + ll;                       // tile 0: j0 = 0
        int sj = jj - NUM_MEM_;
        sj = sj < 0 ? 0 : (sj > N_ - 1 ? N_ - 1 : sj);
        mkc[ct] = mrowp[sj];
        bbc[ct * 4 + 0] = brow0[sj];
        bbc[ct * 4 + 1] = brow1[sj];
        bbc[ct * 4 + 2] = brow2[sj];
        bbc[ct * 4 + 3] = brow3[sj];
    }

    f32x4 oacc[4] = {};          // 4 d-tiles; row = lg*4+r, col(d) = dt*16+ll
    float mrow[4], lsum[4];
    #pragma unroll
    for (int r = 0; r < 4; ++r) { mrow[r] = -1e30f; lsum[r] = 0.f; }

    for (int jt = 0; jt < ntiles; ++jt) {
        int j0 = jt * 64;
        __syncthreads();   // prev tile's PV done reading Ks/Vs
        *(int4*)&Ks[sr][sc]      = kr0;
        *(int4*)&Ks[sr + 32][sc] = kr1;
        *(int4*)&Vs[sr][sc]      = vr0;
        *(int4*)&Vs[sr + 32][sc] = vr1;
        __syncthreads();

        // ---- issue next tile's prefetches (land during this tile's compute) ----
        int jn0 = (jt + 1 < ntiles ? jt + 1 : jt) * 64;
        kr0 = *(const int4*)(KbB + (size_t)(jn0 + sr) * DH_ + sc);
        kr1 = *(const int4*)(KbB + (size_t)(jn0 + sr + 32) * DH_ + sc);
        vr0 = *(const int4*)(VtB + (size_t)sr * JPAD_ + jn0 + sc);
        vr1 = *(const int4*)(VtB + (size_t)(sr + 32) * JPAD_ + jn0 + sc);
        float bbn[16];
        int   mkn[4];
        #pragma unroll
        for (int ct = 0; ct < 4; ++ct) {
            int jj = jn0 + ct * 16 + ll;
            int sj = jj - NUM_MEM_;
            sj = sj < 0 ? 0 : (sj > N_ - 1 ? N_ - 1 : sj);
            mkn[ct] = mrowp[sj];
            bbn[ct * 4 + 0] = brow0[sj];
            bbn[ct * 4 + 1] = brow1[sj];
            bbn[ct * 4 + 2] = brow2[sj];
            bbn[ct * 4 + 3] = brow3[sj];
        }

        // ---- S = Q @ K^T + bias, masked (bias/mask from registers) ----
        float sv[4][4];
        #pragma unroll
        for (int ct = 0; ct < 4; ++ct) {
            f32x4 acc = {};
            short8v bk0 = *(const short8v*)&Ks[ct * 16 + ll][lg * 8];
            short8v bk1 = *(const short8v*)&Ks[ct * 16 + ll][32 + lg * 8];
            acc = __builtin_amdgcn_mfma_f32_16x16x32_bf16(aq0, bk0, acc, 0, 0, 0);
            acc = __builtin_amdgcn_mfma_f32_16x16x32_bf16(aq1, bk1, acc, 0, 0, 0);
            int jj = j0 + ct * 16 + ll;
            #pragma unroll
            for (int r = 0; r < 4; ++r) {
                int i = i_base + lg * 4 + r;
                float withb = mkc[ct] ? acc[r] + bbc[ct * 4 + r] : -1e30f;
                float s = (jj < NUM_MEM_) ? acc[r] : withb;
                sv[ct][r] = (jj <= i + NUM_MEM_) ? s : -1e30f;
            }
        }

        // ---- online softmax ----
        float scale_[4];
        #pragma unroll
        for (int r = 0; r < 4; ++r) {
            float t = fmaxf(fmaxf(sv[0][r], sv[1][r]), fmaxf(sv[2][r], sv[3][r]));
            #pragma unroll
            for (int off = 1; off < 16; off <<= 1) t = fmaxf(t, __shfl_xor(t, off));
            float mn = fmaxf(mrow[r], t);
            scale_[r] = __expf(mrow[r] - mn);
            mrow[r] = mn;
        }
        float psum[4] = {0.f, 0.f, 0.f, 0.f};
        #pragma unroll
        for (int ct = 0; ct < 4; ++ct) {
            #pragma unroll
            for (int r = 0; r < 4; ++r) {
                float p = __expf(sv[ct][r] - mrow[r]);
                psum[r] += p;
                __hip_bfloat16 hb = __float2bfloat16(p);
                Ps[w][lg * 4 + r][ct * 16 + ll] = *(ushort*)&hb;
            }
        }
        #pragma unroll
        for (int r = 0; r < 4; ++r) {
            float t = psum[r];
            #pragma unroll
            for (int off = 1; off < 16; off <<= 1) t += __shfl_xor(t, off);
            lsum[r] = lsum[r] * scale_[r] + t;
        }
        #pragma unroll
        for (int dt = 0; dt < 4; ++dt)
            #pragma unroll
            for (int r = 0; r < 4; ++r) oacc[dt][r] *= scale_[r];

        // ---- O += P @ V ----
        #pragma unroll
        for (int c = 0; c < 2; ++c) {
            short8v ap = *(const short8v*)&Ps[w][ll][c * 32 + lg * 8];
            #pragma unroll
            for (int dt = 0; dt < 4; ++dt) {
                short8v bv = *(const short8v*)&Vs[dt * 16 + ll][c * 32 + lg * 8];
                oacc[dt] = __builtin_amdgcn_mfma_f32_16x16x32_bf16(ap, bv, oacc[dt], 0, 0, 0);
            }
        }

        // rotate prefetched bias/mask into current
        #pragma unroll
        for (int u = 0; u < 16; ++u) bbc[u] = bbn[u];
        #pragma unroll
        for (int u = 0; u < 4; ++u) mkc[u] = mkn[u];
    }

    #pragma unroll
    for (int dt = 0; dt < 4; ++dt) {
        #pragma unroll
        for (int r = 0; r < 4; ++r) {
            int i = i_base + lg * 4 + r;
            attn_out[((size_t)(b * N_ + i)) * QCOLS_ + h * DH_ + dt * 16 + ll] =
                oacc[dt][r] / lsum[r];
        }
    }
}

extern "C" void kernel_launch(void* const* d_in, const int* in_sizes, int n_in,
                              void* d_out, int out_size, void* d_ws, size_t ws_size,
                              hipStream_t stream) {
    const float* x         = (const float*)d_in[0];
    const float* attn_bias = (const float*)d_in[1];
    const float* gamma     = (const float*)d_in[2];
    const float* Wq        = (const float*)d_in[3];
    const float* Wkv       = (const float*)d_in[4];
    const float* mem_kv    = (const float*)d_in[5];
    const float* Wout      = (const float*)d_in[6];
    const int*   mask      = (const int*)d_in[7];
    float* out = (float*)d_out;

    char* wsb = (char*)d_ws;
    float*  xn     = (float*)wsb;                         // [0, 16MB) — freed after gemmQ
    ushort* qb     = (ushort*)wsb;                        // reuse [0, 4MB)
    ushort* Kb     = (ushort*)(wsb + (4u << 20));         // 540KB
    ushort* Vt     = (ushort*)(wsb + (5u << 20));         // 540KB
    float*  q      = (float*)(wsb + (16u << 20));         // 8MB
    float*  kv     = (float*)(wsb + (24u << 20));         // 2MB
    float*  attn_o = (float*)(wsb + (26u << 20));         // 8MB

    ln_kernel<<<ROWS_, 256, 0, stream>>>(x, gamma, xn);
    sgemm64<<<dim3(QCOLS_ / 64, ROWS_ / 64), 256, 0, stream>>>(xn, Wq, q, ROWS_, QCOLS_, DIM_, 0.125f);
    cast_q_kernel<<<(ROWS_ * QCOLS_) / (256 * 8), 256, 0, stream>>>(q, qb);
    sgemm64<<<dim3((2 * DH_) / 64, ROWS_ / 64), 256, 0, stream>>>(x, Wkv, kv, ROWS_, 2 * DH_, DIM_, 1.0f);
    build_kv_kernel<<<(B_ * JPAD_ * DH_) / 256, 256, 0, stream>>>(kv, mem_kv, Kb, Vt);
    fattn_kernel<<<B_ * HEADS_ * (N_ / 64), 256, 0, stream>>>(qb, Kb, Vt, attn_bias, mask, attn_o);
    sgemm64<<<dim3(DIM_ / 64, ROWS_ / 64), 256, 0, stream>>>(attn_o, Wout, out, ROWS_, DIM_, QCOLS_, 1.0f);
}

// Round 4
// 132.617 us; speedup vs baseline: 15.3624x; 1.9908x over previous
//
#include <hip/hip_runtime.h>
#include <hip/hip_bf16.h>
#include <float.h>

#define B_ 2
#define N_ 2048
#define DIM_ 1024
#define HEADS_ 8
#define DH_ 64
#define NUM_MEM_ 4
#define ROWS_ (B_ * N_)          // 4096
#define QCOLS_ (HEADS_ * DH_)    // 512
#define JTOT_ (N_ + NUM_MEM_)    // 2052
#define JPAD_ 2112               // 33 * 64
#define KPAD_ 72                 // fattn LDS row length (bf16 elems), +8 pad

typedef __attribute__((ext_vector_type(8))) short short8v;
typedef __attribute__((ext_vector_type(4))) float f32x4;

static __device__ __forceinline__ ushort f2b(float f) {
    __hip_bfloat16 hb = __float2bfloat16(f);
    return *(ushort*)&hb;
}

// ---------------- LayerNorm + dual bf16 cast: xb = bf16(x), xnb = bf16(LN(x)*gamma) ----------------
__global__ __launch_bounds__(256) void ln_cast_kernel(const float* __restrict__ x,
                                                      const float* __restrict__ gamma,
                                                      ushort* __restrict__ xb,
                                                      ushort* __restrict__ xnb) {
    int row = blockIdx.x;
    const float4 v = ((const float4*)(x + (size_t)row * DIM_))[threadIdx.x];
    float s  = v.x + v.y + v.z + v.w;
    float s2 = v.x * v.x + v.y * v.y + v.z * v.z + v.w * v.w;
    #pragma unroll
    for (int off = 32; off > 0; off >>= 1) {
        s  += __shfl_down(s, off);
        s2 += __shfl_down(s2, off);
    }
    __shared__ float ws1[4], ws2[4];
    int lane = threadIdx.x & 63, wid = threadIdx.x >> 6;
    if (lane == 0) { ws1[wid] = s; ws2[wid] = s2; }
    __syncthreads();
    float tot  = ws1[0] + ws1[1] + ws1[2] + ws1[3];
    float tot2 = ws2[0] + ws2[1] + ws2[2] + ws2[3];
    float mu  = tot * (1.0f / DIM_);
    float var = tot2 * (1.0f / DIM_) - mu * mu;
    float rs  = rsqrtf(var + 1e-5f);
    const float4 g = ((const float4*)gamma)[threadIdx.x];
    float vv[4] = {v.x, v.y, v.z, v.w};
    float gg[4] = {g.x, g.y, g.z, g.w};
    ushort xo[4], xno[4];
    #pragma unroll
    for (int j = 0; j < 4; ++j) {
        xo[j]  = f2b(vv[j]);
        xno[j] = f2b((vv[j] - mu) * rs * gg[j]);
    }
    *(int2*)(xb  + (size_t)row * DIM_ + threadIdx.x * 4) = *(int2*)xo;
    *(int2*)(xnb + (size_t)row * DIM_ + threadIdx.x * 4) = *(int2*)xno;
}

// ---------------- weight cast + transpose: Wt[n][k] = bf16(W[k][n]) ----------------
__global__ __launch_bounds__(256) void wtrans_kernel(const float* __restrict__ W,
                                                     ushort* __restrict__ Wt,
                                                     int K, int N) {
    int t = blockIdx.x * 256 + threadIdx.x;     // over N*K/8
    int n = t % N;
    int k0 = (t / N) * 8;
    ushort u[8];
    #pragma unroll
    for (int j = 0; j < 8; ++j) u[j] = f2b(W[(size_t)(k0 + j) * N + n]);
    *(int4*)(Wt + (size_t)n * K + k0) = *(int4*)u;
}

// ---------------- seed mem slots + zero padding rows of Kb/Vt ----------------
__global__ __launch_bounds__(256) void seed_kv_kernel(const float* __restrict__ mem_kv,
                                                      ushort* __restrict__ Kb,
                                                      ushort* __restrict__ Vt) {
    int t = blockIdx.x * 256 + threadIdx.x;  // 2 * 64 * 64 = 8192
    int d  = t & 63;
    int ji = (t >> 6) & 63;
    int b  = t >> 12;
    int j  = (ji < NUM_MEM_) ? ji : (2048 + ji);   // 2052..2111 pad rows
    float kv_ = 0.f, vv = 0.f;
    if (ji < NUM_MEM_) {
        kv_ = mem_kv[ji * DH_ + d];
        vv  = mem_kv[NUM_MEM_ * DH_ + ji * DH_ + d];
    }
    Kb[((size_t)(b * JPAD_) + j) * DH_ + d] = f2b(kv_);
    Vt[((size_t)(b * DH_) + d) * JPAD_ + j] = f2b(vv);
}

// ---------------- bf16 MFMA GEMM: C = A[M,K] @ Bt[N,K]^T, fused epilogues ----------------
// MODE 0: qb (bf16, *0.125)   MODE 1: Kb / Vt scatter   MODE 2: f32 out
template<int MODE>
__global__ __launch_bounds__(256) void gemm_bf16(const ushort* __restrict__ A,
                                                 const ushort* __restrict__ Bt,
                                                 void* __restrict__ C,
                                                 void* __restrict__ C2,
                                                 int M, int N, int K) {
    __shared__ ushort As[128][40];   // rows padded to 40 bf16 (80B = 20 banks)
    __shared__ ushort Bs[64][40];
    int tid = threadIdx.x;
    int w = tid >> 6, l = tid & 63, lg = l >> 4, ll = l & 15;
    int r0 = blockIdx.y * 128, c0 = blockIdx.x * 64;

    int arow = tid >> 2;           // 0..63
    int achk = (tid & 3) * 8;      // 0,8,16,24
    const ushort* Ap  = A + (size_t)(r0 + arow) * K + achk;
    const ushort* Ap2 = Ap + (size_t)64 * K;
    const ushort* Bp  = Bt + (size_t)(c0 + arow) * K + achk;

    int4 a0 = *(const int4*)Ap;
    int4 a1 = *(const int4*)Ap2;
    int4 b0 = *(const int4*)Bp;

    f32x4 acc[2][4] = {};

    int nk = K / 32;
    for (int ks = 0; ks < nk; ++ks) {
        __syncthreads();
        *(int4*)&As[arow][achk]      = a0;
        *(int4*)&As[arow + 64][achk] = a1;
        *(int4*)&Bs[arow][achk]      = b0;
        __syncthreads();
        int kn = (ks + 1 < nk) ? (ks + 1) * 32 : 0;   // wrap: dummy re-read of tile 0
        a0 = *(const int4*)(Ap + kn);
        a1 = *(const int4*)(Ap2 + kn);
        b0 = *(const int4*)(Bp + kn);
        short8v af[2], bf[4];
        af[0] = *(const short8v*)&As[w * 32 + ll][lg * 8];
        af[1] = *(const short8v*)&As[w * 32 + 16 + ll][lg * 8];
        #pragma unroll
        for (int ct = 0; ct < 4; ++ct)
            bf[ct] = *(const short8v*)&Bs[ct * 16 + ll][lg * 8];
        #pragma unroll
        for (int rt = 0; rt < 2; ++rt)
            #pragma unroll
            for (int ct = 0; ct < 4; ++ct)
                acc[rt][ct] = __builtin_amdgcn_mfma_f32_16x16x32_bf16(af[rt], bf[ct], acc[rt][ct], 0, 0, 0);
    }

    #pragma unroll
    for (int rt = 0; rt < 2; ++rt) {
        #pragma unroll
        for (int ct = 0; ct < 4; ++ct) {
            #pragma unroll
            for (int r = 0; r < 4; ++r) {
                int row = r0 + w * 32 + rt * 16 + lg * 4 + r;
                int col = c0 + ct * 16 + ll;
                float val = acc[rt][ct][r];
                if (MODE == 0) {
                    ((ushort*)C)[(size_t)row * QCOLS_ + col] = f2b(val * 0.125f);
                } else if (MODE == 1) {
                    int b = row >> 11;
                    int j = (row & 2047) + NUM_MEM_;
                    if (col < DH_)
                        ((ushort*)C)[((size_t)(b * JPAD_) + j) * DH_ + col] = f2b(val);
                    else
                        ((ushort*)C2)[((size_t)(b * DH_) + (col - DH_)) * JPAD_ + j] = f2b(val);
                } else {
                    ((float*)C)[(size_t)row * DIM_ + col] = val;
                }
            }
        }
    }
}

// ---------------- flash attention, bf16 MFMA, pipelined ----------------
__global__ __launch_bounds__(256) void fattn_kernel(const ushort* __restrict__ qb,
                                                    const ushort* __restrict__ Kb,
                                                    const ushort* __restrict__ Vt,
                                                    const float* __restrict__ bias,
                                                    const int* __restrict__ mask,
                                                    ushort* __restrict__ attn_out) {
    __shared__ ushort Ks[64][KPAD_];
    __shared__ ushort Vs[64][KPAD_];      // Vs[d][j_local]
    __shared__ ushort Ps[4][16][KPAD_];   // per-wave P tile

    int bid = blockIdx.x;
    int b   = bid >> 8;
    int rem = bid & 255;
    int h   = rem >> 5;
    int qtr = rem & 31;
    int qt  = b ? (31 - qtr) : qtr;
    int q0  = qt * 64;

    int tid = threadIdx.x;
    int w  = tid >> 6;
    int l  = tid & 63;
    int lg = l >> 4;
    int ll = l & 15;
    int i_base = q0 + w * 16;

    short8v aq0, aq1;
    {
        int i = i_base + ll;
        const ushort* qp = qb + ((size_t)(b * N_ + i)) * QCOLS_ + h * DH_;
        aq0 = *(const short8v*)(qp + lg * 8);
        aq1 = *(const short8v*)(qp + 32 + lg * 8);
    }

    const float* brow0 = bias + ((size_t)h * N_ + i_base + lg * 4 + 0) * N_;
    const float* brow1 = bias + ((size_t)h * N_ + i_base + lg * 4 + 1) * N_;
    const float* brow2 = bias + ((size_t)h * N_ + i_base + lg * 4 + 2) * N_;
    const float* brow3 = bias + ((size_t)h * N_ + i_base + lg * 4 + 3) * N_;
    const int* mrowp = mask + b * N_;

    int ntiles = (q0 + 67) / 64 + 1;

    int sr = tid >> 3, sc = (tid & 7) * 8;
    const ushort* KbB = Kb + (size_t)b * JPAD_ * DH_;
    const ushort* VtB = Vt + (size_t)b * DH_ * JPAD_;

    int4 kr0 = *(const int4*)(KbB + (size_t)sr * DH_ + sc);
    int4 kr1 = *(const int4*)(KbB + (size_t)(sr + 32) * DH_ + sc);
    int4 vr0 = *(const int4*)(VtB + (size_t)sr * JPAD_ + sc);
    int4 vr1 = *(const int4*)(VtB + (size_t)(sr + 32) * JPAD_ + sc);
    float bbc[16];
    int   mkc[4];
    #pragma unroll
    for (int ct = 0; ct < 4; ++ct) {
        int jj = ct * 16 + ll;
        int sj = jj - NUM_MEM_;
        sj = sj < 0 ? 0 : (sj > N_ - 1 ? N_ - 1 : sj);
        mkc[ct] = mrowp[sj];
        bbc[ct * 4 + 0] = brow0[sj];
        bbc[ct * 4 + 1] = brow1[sj];
        bbc[ct * 4 + 2] = brow2[sj];
        bbc[ct * 4 + 3] = brow3[sj];
    }

    f32x4 oacc[4] = {};
    float mrow[4], lsum[4];
    #pragma unroll
    for (int r = 0; r < 4; ++r) { mrow[r] = -1e30f; lsum[r] = 0.f; }

    for (int jt = 0; jt < ntiles; ++jt) {
        int j0 = jt * 64;
        __syncthreads();
        *(int4*)&Ks[sr][sc]      = kr0;
        *(int4*)&Ks[sr + 32][sc] = kr1;
        *(int4*)&Vs[sr][sc]      = vr0;
        *(int4*)&Vs[sr + 32][sc] = vr1;
        __syncthreads();

        int jn0 = (jt + 1 < ntiles ? jt + 1 : jt) * 64;
        kr0 = *(const int4*)(KbB + (size_t)(jn0 + sr) * DH_ + sc);
        kr1 = *(const int4*)(KbB + (size_t)(jn0 + sr + 32) * DH_ + sc);
        vr0 = *(const int4*)(VtB + (size_t)sr * JPAD_ + jn0 + sc);
        vr1 = *(const int4*)(VtB + (size_t)(sr + 32) * JPAD_ + jn0 + sc);
        float bbn[16];
        int   mkn[4];
        #pragma unroll
        for (int ct = 0; ct < 4; ++ct) {
            int jj = jn0 + ct * 16 + ll;
            int sj = jj - NUM_MEM_;
            sj = sj < 0 ? 0 : (sj > N_ - 1 ? N_ - 1 : sj);
            mkn[ct] = mrowp[sj];
            bbn[ct * 4 + 0] = brow0[sj];
            bbn[ct * 4 + 1] = brow1[sj];
            bbn[ct * 4 + 2] = brow2[sj];
            bbn[ct * 4 + 3] = brow3[sj];
        }

        float sv[4][4];
        #pragma unroll
        for (int ct = 0; ct < 4; ++ct) {
            f32x4 acc = {};
            short8v bk0 = *(const short8v*)&Ks[ct * 16 + ll][lg * 8];
            short8v bk1 = *(const short8v*)&Ks[ct * 16 + ll][32 + lg * 8];
            acc = __builtin_amdgcn_mfma_f32_16x16x32_bf16(aq0, bk0, acc, 0, 0, 0);
            acc = __builtin_amdgcn_mfma_f32_16x16x32_bf16(aq1, bk1, acc, 0, 0, 0);
            int jj = j0 + ct * 16 + ll;
            #pragma unroll
            for (int r = 0; r < 4; ++r) {
                int i = i_base + lg * 4 + r;
                float withb = mkc[ct] ? acc[r] + bbc[ct * 4 + r] : -1e30f;
                float s = (jj < NUM_MEM_) ? acc[r] : withb;
                sv[ct][r] = (jj <= i + NUM_MEM_) ? s : -1e30f;
            }
        }

        float scale_[4];
        #pragma unroll
        for (int r = 0; r < 4; ++r) {
            float t = fmaxf(fmaxf(sv[0][r], sv[1][r]), fmaxf(sv[2][r], sv[3][r]));
            #pragma unroll
            for (int off = 1; off < 16; off <<= 1) t = fmaxf(t, __shfl_xor(t, off));
            float mn = fmaxf(mrow[r], t);
            scale_[r] = __expf(mrow[r] - mn);
            mrow[r] = mn;
        }
        float psum[4] = {0.f, 0.f, 0.f, 0.f};
        #pragma unroll
        for (int ct = 0; ct < 4; ++ct) {
            #pragma unroll
            for (int r = 0; r < 4; ++r) {
                float p = __expf(sv[ct][r] - mrow[r]);
                psum[r] += p;
                Ps[w][lg * 4 + r][ct * 16 + ll] = f2b(p);
            }
        }
        #pragma unroll
        for (int r = 0; r < 4; ++r) {
            float t = psum[r];
            #pragma unroll
            for (int off = 1; off < 16; off <<= 1) t += __shfl_xor(t, off);
            lsum[r] = lsum[r] * scale_[r] + t;
        }
        #pragma unroll
        for (int dt = 0; dt < 4; ++dt)
            #pragma unroll
            for (int r = 0; r < 4; ++r) oacc[dt][r] *= scale_[r];

        #pragma unroll
        for (int c = 0; c < 2; ++c) {
            short8v ap = *(const short8v*)&Ps[w][ll][c * 32 + lg * 8];
            #pragma unroll
            for (int dt = 0; dt < 4; ++dt) {
                short8v bv = *(const short8v*)&Vs[dt * 16 + ll][c * 32 + lg * 8];
                oacc[dt] = __builtin_amdgcn_mfma_f32_16x16x32_bf16(ap, bv, oacc[dt], 0, 0, 0);
            }
        }

        #pragma unroll
        for (int u = 0; u < 16; ++u) bbc[u] = bbn[u];
        #pragma unroll
        for (int u = 0; u < 4; ++u) mkc[u] = mkn[u];
    }

    #pragma unroll
    for (int dt = 0; dt < 4; ++dt) {
        #pragma unroll
        for (int r = 0; r < 4; ++r) {
            int i = i_base + lg * 4 + r;
            attn_out[((size_t)(b * N_ + i)) * QCOLS_ + h * DH_ + dt * 16 + ll] =
                f2b(oacc[dt][r] / lsum[r]);
        }
    }
}

extern "C" void kernel_launch(void* const* d_in, const int* in_sizes, int n_in,
                              void* d_out, int out_size, void* d_ws, size_t ws_size,
                              hipStream_t stream) {
    const float* x         = (const float*)d_in[0];
    const float* attn_bias = (const float*)d_in[1];
    const float* gamma     = (const float*)d_in[2];
    const float* Wq        = (const float*)d_in[3];
    const float* Wkv       = (const float*)d_in[4];
    const float* mem_kv    = (const float*)d_in[5];
    const float* Wout      = (const float*)d_in[6];
    const int*   mask      = (const int*)d_in[7];
    float* out = (float*)d_out;

    char* wsb = (char*)d_ws;
    ushort* xb      = (ushort*)wsb;                    // 8 MB
    ushort* xnb     = (ushort*)(wsb + (8u  << 20));    // 8 MB
    ushort* qb      = (ushort*)(wsb + (16u << 20));    // 4 MB
    ushort* attn_ob = (ushort*)(wsb + (20u << 20));    // 4 MB
    ushort* Kb      = (ushort*)(wsb + (24u << 20));    // 0.52 MB
    ushort* Vt      = (ushort*)(wsb + (25u << 20));    // 0.52 MB
    ushort* Wqt     = (ushort*)(wsb + (26u << 20));    // 1 MB
    ushort* Wkvt    = (ushort*)(wsb + (27u << 20));    // 0.25 MB
    ushort* Woutt   = (ushort*)(wsb + (28u << 20));    // 1 MB

    ln_cast_kernel<<<ROWS_, 256, 0, stream>>>(x, gamma, xb, xnb);
    wtrans_kernel<<<(DIM_ * QCOLS_) / (8 * 256), 256, 0, stream>>>(Wq, Wqt, DIM_, QCOLS_);
    wtrans_kernel<<<(DIM_ * 2 * DH_) / (8 * 256), 256, 0, stream>>>(Wkv, Wkvt, DIM_, 2 * DH_);
    wtrans_kernel<<<(QCOLS_ * DIM_) / (8 * 256), 256, 0, stream>>>(Wout, Woutt, QCOLS_, DIM_);

    gemm_bf16<0><<<dim3(QCOLS_ / 64, ROWS_ / 128), 256, 0, stream>>>(xnb, Wqt, qb, nullptr, ROWS_, QCOLS_, DIM_);
    gemm_bf16<1><<<dim3((2 * DH_) / 64, ROWS_ / 128), 256, 0, stream>>>(xb, Wkvt, Kb, Vt, ROWS_, 2 * DH_, DIM_);
    seed_kv_kernel<<<32, 256, 0, stream>>>(mem_kv, Kb, Vt);
    fattn_kernel<<<B_ * HEADS_ * (N_ / 64), 256, 0, stream>>>(qb, Kb, Vt, attn_bias, mask, attn_ob);
    gemm_bf16<2><<<dim3(DIM_ / 64, ROWS_ / 128), 256, 0, stream>>>(attn_ob, Woutt, out, nullptr, ROWS_, DIM_, QCOLS_);
}